// Round 1
// baseline (149.846 us; speedup 1.0000x reference)
//
#include <hip/hip_runtime.h>

// cyclicLoss: out = mean((input-target)^2) + 0.1*sqrt( sum_{i<(N-1)*T} (input[i]-input[i+T])^2 )
// fp32, n = N*T = 2048*8192 = 16.8M elements (64 MB each array).
//
// R7 = R6 (42-45us kernel) + true in-flight loads + two block generations:
//   - Evidence (R6 rocprof): VGPR_Count=32 -> the compiler re-rounded R6's
//     "17 independent loads" into ~4 serialized wait-rounds (17 float4 need
//     68 dest VGPRs; at 32 they can't be live). OccupancyPercent=53% ->
//     one-generation grid (8 blocks/CU, one-shot) drains into a half-empty
//     tail. Both throttle lines-in-flight; kernel sits at 5.5 B/cyc/CU vs
//     copy's 10.7.
//   - Fix: RSEG 8->4. Load set = 5 input rows + 4 target rows = 9 float4 =
//     36 dest VGPRs -> whole burst stays register-resident and issued
//     before any vmcnt (real 9-deep MLP/wave). GRID 2048->4096 = 16
//     blocks/CU queued -> second generation issues while first drains.
//   - Traffic: input read 1.25x -> 144 MB logical (vs 136). Measured
//     traffic-insensitivity (R5->R6: 1.41x traffic -> 1.05x time) says
//     this costs ~nothing; MLP/tail is the lever.
//   - Keep: no fence/ticket (R1-R3), plain-store partials (R5), separate
//     tiny finalize dispatch, wave-uniform boundary clamp + cndmask,
//     generic fallback for non-decomposing shapes.

#define LAMDA 0.1
#define BLOCK 256
#define GRID 4096
#define RSEG 4

__global__ __launch_bounds__(BLOCK, 4) void cyclic_reduce_kernel(
    const float4* __restrict__ in4,
    const float4* __restrict__ tg4,
    const int* __restrict__ pT,
    const int* __restrict__ pN,
    long long n,
    double* __restrict__ m_part,   // [GRID]
    double* __restrict__ d_part)   // [GRID]
{
    const int T = pT[0];
    const int N = pN[0];
    const int n4 = (int)(n >> 2);
    const int t4 = T >> 2;
    const long long limit = (N > 1) ? (long long)(N - 1) * (long long)T : 0;
    const int limit4 = (int)(limit >> 2);

    float mse_acc = 0.0f;
    float dif_acc = 0.0f;

    // ---- fast-path shape check (wave-uniform scalar) ----
    const int colchunks = (T % 4 == 0) ? (t4 / BLOCK) : 0;
    bool fast = (colchunks > 0) && (t4 % BLOCK == 0)
             && ((long long)N * (long long)T == n)
             && ((int)gridDim.x % colchunks == 0);
    int rowsegs = 0;
    if (fast) {
        rowsegs = (int)gridDim.x / colchunks;
        fast = (rowsegs > 0) && (N % rowsegs == 0) && (N / rowsegs == RSEG);
    }

    if (fast) {
        const int seg      = (int)blockIdx.x;
        const int colchunk = seg % colchunks;
        const int rowseg   = seg / colchunks;
        const int row0     = rowseg * RSEG;
        const int col4     = colchunk * BLOCK + (int)threadIdx.x;
        const float4* px = in4 + (long long)row0 * t4 + col4;
        const float4* pt = tg4 + (long long)row0 * t4 + col4;

        // boundary input row: clamped for the last segment (wave-uniform)
        const bool hasb = (row0 + RSEG < N);
        const int  ofsb = hasb ? RSEG * t4 : (RSEG - 1) * t4;

        // 9 independent loads, all destinations live simultaneously
        // (36 VGPRs of load data -- fits; do NOT grow RSEG past the point
        // where the compiler starts re-rounding, that was R6's stall).
        float4 x[RSEG + 1];
        float4 b[RSEG];
        #pragma unroll
        for (int k = 0; k < RSEG; ++k) x[k] = px[k * t4];
        x[RSEG] = px[ofsb];
        #pragma unroll
        for (int k = 0; k < RSEG; ++k) b[k] = pt[k * t4];

        #pragma unroll
        for (int k = 0; k < RSEG; ++k) {
            float e0 = x[k].x - b[k].x, e1 = x[k].y - b[k].y;
            float e2 = x[k].z - b[k].z, e3 = x[k].w - b[k].w;
            mse_acc += e0 * e0 + e1 * e1 + e2 * e2 + e3 * e3;
        }
        #pragma unroll
        for (int k = 0; k < RSEG - 1; ++k) {
            float d0 = x[k].x - x[k + 1].x, d1 = x[k].y - x[k + 1].y;
            float d2 = x[k].z - x[k + 1].z, d3 = x[k].w - x[k + 1].w;
            dif_acc += d0 * d0 + d1 * d1 + d2 * d2 + d3 * d3;
        }
        {
            float d0 = x[RSEG - 1].x - x[RSEG].x, d1 = x[RSEG - 1].y - x[RSEG].y;
            float d2 = x[RSEG - 1].z - x[RSEG].z, d3 = x[RSEG - 1].w - x[RSEG].w;
            float dd = d0 * d0 + d1 * d1 + d2 * d2 + d3 * d3;
            dif_acc += hasb ? dd : 0.0f;
        }
    } else {
        // ---- generic fallback: R5's flat region-split loops ----
        const int nth  = (int)gridDim.x * BLOCK;
        const int gtid = (int)blockIdx.x * BLOCK + (int)threadIdx.x;

        int i = gtid;
        for (; i + 3 * nth < limit4; i += 4 * nth) {
            const int i1 = i + nth, i2 = i + 2 * nth, i3 = i + 3 * nth;
            float4 a0 = in4[i];        float4 c0 = in4[i + t4];
            float4 a1 = in4[i1];       float4 c1 = in4[i1 + t4];
            float4 a2 = in4[i2];       float4 c2 = in4[i2 + t4];
            float4 a3 = in4[i3];       float4 c3 = in4[i3 + t4];
            float4 b0 = tg4[i];        float4 b1 = tg4[i1];
            float4 b2 = tg4[i2];       float4 b3 = tg4[i3];

            float e0, e1, e2, e3, d0, d1, d2, d3;
            e0 = a0.x - b0.x; e1 = a0.y - b0.y; e2 = a0.z - b0.z; e3 = a0.w - b0.w;
            mse_acc += e0 * e0 + e1 * e1 + e2 * e2 + e3 * e3;
            d0 = a0.x - c0.x; d1 = a0.y - c0.y; d2 = a0.z - c0.z; d3 = a0.w - c0.w;
            dif_acc += d0 * d0 + d1 * d1 + d2 * d2 + d3 * d3;
            e0 = a1.x - b1.x; e1 = a1.y - b1.y; e2 = a1.z - b1.z; e3 = a1.w - b1.w;
            mse_acc += e0 * e0 + e1 * e1 + e2 * e2 + e3 * e3;
            d0 = a1.x - c1.x; d1 = a1.y - c1.y; d2 = a1.z - c1.z; d3 = a1.w - c1.w;
            dif_acc += d0 * d0 + d1 * d1 + d2 * d2 + d3 * d3;
            e0 = a2.x - b2.x; e1 = a2.y - b2.y; e2 = a2.z - b2.z; e3 = a2.w - b2.w;
            mse_acc += e0 * e0 + e1 * e1 + e2 * e2 + e3 * e3;
            d0 = a2.x - c2.x; d1 = a2.y - c2.y; d2 = a2.z - c2.z; d3 = a2.w - c2.w;
            dif_acc += d0 * d0 + d1 * d1 + d2 * d2 + d3 * d3;
            e0 = a3.x - b3.x; e1 = a3.y - b3.y; e2 = a3.z - b3.z; e3 = a3.w - b3.w;
            mse_acc += e0 * e0 + e1 * e1 + e2 * e2 + e3 * e3;
            d0 = a3.x - c3.x; d1 = a3.y - c3.y; d2 = a3.z - c3.z; d3 = a3.w - c3.w;
            dif_acc += d0 * d0 + d1 * d1 + d2 * d2 + d3 * d3;
        }
        for (; i < limit4; i += nth) {
            float4 a = in4[i];
            float4 c = in4[i + t4];
            float4 b = tg4[i];
            float e0 = a.x - b.x, e1 = a.y - b.y, e2 = a.z - b.z, e3 = a.w - b.w;
            mse_acc += e0 * e0 + e1 * e1 + e2 * e2 + e3 * e3;
            float d0 = a.x - c.x, d1 = a.y - c.y, d2 = a.z - c.z, d3 = a.w - c.w;
            dif_acc += d0 * d0 + d1 * d1 + d2 * d2 + d3 * d3;
        }
        for (int k = limit4 + gtid; k < n4; k += nth) {
            float4 a = in4[k];
            float4 b = tg4[k];
            float e0 = a.x - b.x, e1 = a.y - b.y, e2 = a.z - b.z, e3 = a.w - b.w;
            mse_acc += e0 * e0 + e1 * e1 + e2 * e2 + e3 * e3;
        }
        {
            const float* in = (const float*)in4;
            const float* tg = (const float*)tg4;
            long long idx = ((long long)n4 << 2) + gtid;
            if (idx < n) {
                float e = in[idx] - tg[idx];
                mse_acc += e * e;
            }
            long long didx = ((long long)limit4 << 2) + gtid;
            if (didx < limit) {
                float d = in[didx] - in[didx + T];
                dif_acc += d * d;
            }
        }
    }

    // ---- block reduction: wave-64 shuffle, then LDS across 4 waves ----
    #pragma unroll
    for (int off = 32; off > 0; off >>= 1) {
        mse_acc += __shfl_down(mse_acc, off, 64);
        dif_acc += __shfl_down(dif_acc, off, 64);
    }
    __shared__ float s_m[4], s_d[4];
    const int wave = threadIdx.x >> 6;
    if ((threadIdx.x & 63) == 0) { s_m[wave] = mse_acc; s_d[wave] = dif_acc; }
    __syncthreads();
    if (threadIdx.x == 0) {
        m_part[blockIdx.x] = (double)s_m[0] + (double)s_m[1] + (double)s_m[2] + (double)s_m[3];
        d_part[blockIdx.x] = (double)s_d[0] + (double)s_d[1] + (double)s_d[2] + (double)s_d[3];
    }
}

#define FBLOCK 1024

__global__ __launch_bounds__(FBLOCK) void cyclic_finalize_kernel(
    const double* __restrict__ m_part,
    const double* __restrict__ d_part,
    const int* __restrict__ pN,
    float* __restrict__ out,
    long long n,
    int nparts)
{
    double m = 0.0, d = 0.0;
    for (int i = threadIdx.x; i < nparts; i += FBLOCK) {
        m += m_part[i];
        d += d_part[i];
    }
    #pragma unroll
    for (int off = 32; off > 0; off >>= 1) {
        m += __shfl_down(m, off, 64);
        d += __shfl_down(d, off, 64);
    }
    __shared__ double f_m[FBLOCK / 64], f_d[FBLOCK / 64];
    const int wave = threadIdx.x >> 6;
    if ((threadIdx.x & 63) == 0) { f_m[wave] = m; f_d[wave] = d; }
    __syncthreads();
    if (threadIdx.x == 0) {
        double mt = 0.0, dt = 0.0;
        #pragma unroll
        for (int w = 0; w < FBLOCK / 64; ++w) { mt += f_m[w]; dt += f_d[w]; }
        double mse = mt / (double)n;
        double nom = (pN[0] != 1) ? (LAMDA * sqrt(dt)) : 0.0;
        out[0] = (float)(mse + nom);
    }
}

extern "C" void kernel_launch(void* const* d_in, const int* in_sizes, int n_in,
                              void* d_out, int out_size, void* d_ws, size_t ws_size,
                              hipStream_t stream) {
    const float* input  = (const float*)d_in[0];
    const float* target = (const float*)d_in[1];
    const int*   pT     = (const int*)d_in[2];
    const int*   pN     = (const int*)d_in[3];
    float* out = (float*)d_out;

    const long long n = (long long)in_sizes[0];

    double* m_part = (double*)d_ws;
    double* d_part = m_part + GRID;

    cyclic_reduce_kernel<<<GRID, BLOCK, 0, stream>>>(
        (const float4*)input, (const float4*)target, pT, pN, n, m_part, d_part);

    cyclic_finalize_kernel<<<1, FBLOCK, 0, stream>>>(m_part, d_part, pN, out, n, GRID);
}